// Round 16
// baseline (176.713 us; speedup 1.0000x reference)
//
#include <hip/hip_runtime.h>

#define F 128            // F_IN == F_OUT == 128
#define EPSV 1e-5f
#define NPB 256          // scatter blocks (phase A)
#define CAP 5120         // max edges per 128-node bucket (mean 2048)

typedef _Float16 f16x8 __attribute__((ext_vector_type(8)));
typedef _Float16 f16x4 __attribute__((ext_vector_type(4)));
typedef _Float16 f16x2 __attribute__((ext_vector_type(2)));
typedef float    f32x4 __attribute__((ext_vector_type(4)));

#define SRCMASK 0x1FFFFFF   // low 25 bits: src id; bits 25..31: dst&127

// ---------------- Phase 0 (fused): cvt_x | cvt_w | pa1 histogram ------------
__global__ __launch_bounds__(256) void k_phase0(
        const float* __restrict__ x, _Float16* __restrict__ xh, int n4x,
        const float* __restrict__ W, _Float16* __restrict__ wh, int n4w,
        const int* __restrict__ dst, int* __restrict__ histA,
        int E, int Epb, int NF, int nbx) {
    int t = threadIdx.x, b = blockIdx.x;
    if (b < NPB) {
        __shared__ int h[512];
        h[t] = 0; h[t + 256] = 0;
        __syncthreads();
        int beg = b * Epb;
        int end = min(beg + Epb, E);
        for (int i = beg + t; i < end; i += 256)
            atomicAdd(&h[dst[i] >> 7], 1);
        __syncthreads();
        for (int f = t; f < NF; f += 256)
            histA[f * NPB + b] = h[f];
    } else if (b < NPB + nbx) {
        int i = (b - NPB) * 256 + t;
        if (i >= n4x) return;
        float4 v = *reinterpret_cast<const float4*>(x + (size_t)i * 4);
        f16x4 o = { (_Float16)v.x, (_Float16)v.y, (_Float16)v.z, (_Float16)v.w };
        *reinterpret_cast<f16x4*>(xh + (size_t)i * 4) = o;
    } else {
        int i = (b - NPB - nbx) * 256 + t;
        if (i >= n4w) return;
        float4 v = *reinterpret_cast<const float4*>(W + (size_t)i * 4);
        f16x4 o = { (_Float16)v.x, (_Float16)v.y, (_Float16)v.z, (_Float16)v.w };
        *reinterpret_cast<f16x4*>(wh + (size_t)i * 4) = o;
    }
}

// ---------------- Phase A2a: per-bucket exclusive scan over the NPB blocks --
__global__ __launch_bounds__(256) void k_pa2a(
        const int* __restrict__ histA, int* __restrict__ cursorRel,
        int* __restrict__ tot) {
    __shared__ int wsum[4];
    int f = blockIdx.x, t = threadIdx.x;
    int lane = t & 63, wv = t >> 6;
    int v = histA[f * NPB + t];
    int sc = v;
    #pragma unroll
    for (int off = 1; off < 64; off <<= 1) {
        int o = __shfl_up(sc, off);
        if (lane >= off) sc += o;
    }
    if (lane == 63) wsum[wv] = sc;
    __syncthreads();
    int woff = 0;
    for (int i = 0; i < wv; ++i) woff += wsum[i];
    cursorRel[f * NPB + t] = woff + sc - v;
    if (t == 255) tot[f] = woff + sc;
}

// ---------------- Phase A2b: scan bucket totals -> bktptr; zero stats -------
__global__ __launch_bounds__(256) void k_pa2b(
        const int* __restrict__ tot, int* __restrict__ bktptr,
        float* __restrict__ stats, int NF) {
    int t = threadIdx.x;
    stats[t] = 0.f;
    if (t < 64) {
        int carry = 0;
        for (int base = 0; base < NF; base += 64) {
            int i = base + t;
            int v = (i < NF) ? tot[i] : 0;
            int sc = v;
            #pragma unroll
            for (int off = 1; off < 64; off <<= 1) {
                int o = __shfl_up(sc, off);
                if (t >= off) sc += o;
            }
            if (i < NF) bktptr[i] = carry + sc - v;
            carry += __shfl(sc, 63);
        }
        if (t == 0) bktptr[NF] = carry;   // == E
    }
}

// ---------------- Phase A3: scatter packed payload into bucket order --------
__global__ __launch_bounds__(256) void k_pa3(
        const int* __restrict__ dst, const int* __restrict__ src,
        const float* __restrict__ we, const int* __restrict__ cursorRel,
        const int* __restrict__ bktptr,
        int2* __restrict__ payload, int E, int Epb, int NF) {
    __shared__ int cur[512];
    int t = threadIdx.x, b = blockIdx.x;
    for (int f = t; f < NF; f += 256)
        cur[f] = bktptr[f] + cursorRel[f * NPB + b];
    __syncthreads();
    int beg = b * Epb;                       // Epb % 4 == 0 -> 16B-aligned
    int end = min(beg + Epb, E);
    for (int i0 = beg + t * 4; i0 < end; i0 += 1024) {
        int d[4], s[4]; float w[4];
        if (i0 + 3 < end) {
            int4   d4 = *reinterpret_cast<const int4*>(dst + i0);
            int4   s4 = *reinterpret_cast<const int4*>(src + i0);
            float4 w4 = *reinterpret_cast<const float4*>(we + i0);
            d[0] = d4.x; d[1] = d4.y; d[2] = d4.z; d[3] = d4.w;
            s[0] = s4.x; s[1] = s4.y; s[2] = s4.z; s[3] = s4.w;
            w[0] = w4.x; w[1] = w4.y; w[2] = w4.z; w[3] = w4.w;
        } else {
            #pragma unroll
            for (int u = 0; u < 4; ++u) {
                int i = min(i0 + u, E - 1);
                d[u] = dst[i]; s[u] = src[i]; w[u] = we[i];
            }
        }
        int slot[4];
        #pragma unroll
        for (int u = 0; u < 4; ++u)
            if (i0 + u < end) slot[u] = atomicAdd(&cur[d[u] >> 7], 1);
        #pragma unroll
        for (int u = 0; u < 4; ++u)
            if (i0 + u < end)
                payload[slot[u]] = make_int2(s[u] | ((d[u] & 127) << 25),
                                             __float_as_int(w[u]));
    }
}

// ---------------- Fused sort + aggregate: one block per 128-node bucket -----
// Phase 1: counting-sort bucket edges into LDS (node order).
// Phase 2: 8 waves x 16 nodes; PAIRED-ROW gather (f16x4, 2 rows/instr):
//   lanes 0-31 handle even edges, lanes 32-63 odd edges; shfl_xor(32) folds.
__global__ __launch_bounds__(512) void k_sortagg(
        const _Float16* __restrict__ xh, const int* __restrict__ bktptr,
        const int2* __restrict__ payload, _Float16* __restrict__ aggh, int N) {
    __shared__ int2 pl[CAP];                  // 40 KB
    __shared__ int h[128], hs[129], cur[128];
    int t = threadIdx.x, f = blockIdx.x;
    int beg = bktptr[f], end = bktptr[f + 1];
    int cnt = min(end - beg, CAP);
    if (t < 128) h[t] = 0;
    __syncthreads();
    for (int i = t; i < cnt; i += 512)
        atomicAdd(&h[(payload[beg + i].x >> 25) & 127], 1);
    __syncthreads();
    if (t < 64) {   // wave 0: exclusive scan of h[0..128)
        int v0 = h[t], s0 = v0;
        #pragma unroll
        for (int off = 1; off < 64; off <<= 1) {
            int o = __shfl_up(s0, off);
            if (t >= off) s0 += o;
        }
        int tot0 = __shfl(s0, 63);
        hs[t] = s0 - v0;
        int v1 = h[64 + t], s1 = v1;
        #pragma unroll
        for (int off = 1; off < 64; off <<= 1) {
            int o = __shfl_up(s1, off);
            if (t >= off) s1 += o;
        }
        hs[64 + t] = tot0 + s1 - v1;
    }
    __syncthreads();
    if (t < 128) cur[t] = hs[t];
    if (t == 128) hs[128] = cnt;
    __syncthreads();
    for (int i = t; i < cnt; i += 512) {
        int2 p = payload[beg + i];
        int r = (p.x >> 25) & 127;
        int pos = atomicAdd(&cur[r], 1);
        pl[pos] = p;
    }
    __syncthreads();

    int wv = t >> 6, lane = t & 63;
    int half = lane >> 5, cl = lane & 31;
    int row0 = f << 7;
    #pragma unroll 1
    for (int k = 0; k < 16; ++k) {
        int r = wv * 16 + k;
        int n = row0 + r;
        if (n >= N) break;
        int b0 = hs[r], b1 = hs[r + 1];
        f32x4 acc = {0.f, 0.f, 0.f, 0.f};
        for (int i = b0; i < b1; i += 8) {
            int2 p[8];
            #pragma unroll
            for (int u = 0; u < 8; ++u)
                p[u] = pl[min(i + u, cnt - 1)];
            #pragma unroll
            for (int q = 0; q < 4; ++q) {
                int ex = half ? p[2 * q + 1].x : p[2 * q].x;   // v_cndmask, no scratch
                int ey = half ? p[2 * q + 1].y : p[2 * q].y;
                float wq = (i + 2 * q + half < b1) ? __int_as_float(ey) : 0.f;
                f16x4 v = *reinterpret_cast<const f16x4*>(
                    xh + (size_t)(ex & SRCMASK) * F + cl * 4);
                acc[0] += wq * (float)v[0];
                acc[1] += wq * (float)v[1];
                acc[2] += wq * (float)v[2];
                acc[3] += wq * (float)v[3];
            }
        }
        #pragma unroll
        for (int j = 0; j < 4; ++j)
            acc[j] += __shfl_xor(acc[j], 32);
        if (half == 0) {
            f16x4 o = { (_Float16)acc[0], (_Float16)acc[1],
                        (_Float16)acc[2], (_Float16)acc[3] };
            *reinterpret_cast<f16x4*>(aggh + (size_t)n * F + cl * 4) = o;
        }
    }
}

// ---------------- MFMA GEMM: 512 thr / 8 waves, 16 rows per wave ------------
__global__ __launch_bounds__(512) void k_gemm_mfma(
        const _Float16* __restrict__ xh, const _Float16* __restrict__ aggh,
        const _Float16* __restrict__ wh, _Float16* __restrict__ yh,
        float* __restrict__ colsum, float* __restrict__ colsumsq, int N) {
    __shared__ _Float16 lds_w[32768];                 // 64 KB, XOR-swizzled
    __shared__ float lds_s[8][128], lds_q[8][128];
    int t = threadIdx.x, w = t >> 6, l = t & 63;
    int lo16 = l & 15, hi4 = l >> 4;

    // stage W: 4096 chunks of 16B (8 f16); 32 chunks per 512B row.
    #pragma unroll
    for (int i = 0; i < 8; ++i) {
        int c = i * 512 + t;
        int o = c >> 5, kc = c & 31;
        f16x8 v = *reinterpret_cast<const f16x8*>(wh + (size_t)c * 8);
        int byte = (o * 512 + kc * 16) ^ ((o & 7) << 4);
        *reinterpret_cast<f16x8*>((char*)lds_w + byte) = v;
    }
    __syncthreads();

    int rows0 = blockIdx.x * 128 + w * 16;
    int ra0 = rows0 + lo16;
    if (ra0 >= N) ra0 = N - 1;                // clamp; discarded in epilogue

    f32x4 acc0[8] = {};
    #pragma unroll
    for (int kb = 0; kb < 8; ++kb) {
        const _Float16* base = (kb < 4) ? xh : aggh;
        int koff = (kb & 3) * 32 + hi4 * 8;
        f16x8 a0 = *reinterpret_cast<const f16x8*>(base + (size_t)ra0 * F + koff);
        #pragma unroll
        for (int ct = 0; ct < 8; ++ct) {
            int o = ct * 16 + lo16;
            int byte = (o * 512 + kb * 64 + hi4 * 16) ^ ((o & 7) << 4);
            f16x8 b = *reinterpret_cast<const f16x8*>((char*)lds_w + byte);
            acc0[ct] = __builtin_amdgcn_mfma_f32_16x16x32_f16(a0, b, acc0[ct], 0, 0, 0);
        }
    }

    #pragma unroll
    for (int ct = 0; ct < 8; ++ct) {
        float sv = 0.f, qv = 0.f;
        int col = ct * 16 + lo16;
        #pragma unroll
        for (int r = 0; r < 4; ++r) {
            int row0 = rows0 + hi4 * 4 + r;
            float v0 = acc0[ct][r];
            if (row0 < N) {
                yh[(size_t)row0 * F + col] = (_Float16)v0;
                sv += v0; qv += v0 * v0;
            }
        }
        sv += __shfl_xor(sv, 16); sv += __shfl_xor(sv, 32);
        qv += __shfl_xor(qv, 16); qv += __shfl_xor(qv, 32);
        if (l < 16) {
            lds_s[w][col] = sv;
            lds_q[w][col] = qv;
        }
    }
    __syncthreads();
    if (t < 128) {
        float S = 0.f, Q = 0.f;
        #pragma unroll
        for (int wv = 0; wv < 8; ++wv) {
            S += lds_s[wv][t];
            Q += lds_q[wv][t];
        }
        atomicAdd(&colsum[t], S);
        atomicAdd(&colsumsq[t], Q);
    }
}

// ---------------- BatchNorm: finalize + normalize (f16 y -> f32 out) --------
__global__ __launch_bounds__(256) void k_norm(
        const _Float16* __restrict__ yh, float* __restrict__ out,
        const float* __restrict__ colsum, const float* __restrict__ colsumsq,
        const float* __restrict__ gamma, const float* __restrict__ beta,
        float ninv, int total8) {
    __shared__ float sc_sh[F], sh_sh[F];
    int t = threadIdx.x;
    if (t < F) {
        float mean = colsum[t] * ninv;
        float var = colsumsq[t] * ninv - mean * mean;
        float rstd = rsqrtf(var + EPSV);
        float sc = gamma[t] * rstd;
        sc_sh[t] = sc;
        sh_sh[t] = beta[t] - mean * sc;
    }
    __syncthreads();
    int idx = blockIdx.x * 256 + t;
    if (idx >= total8) return;
    int col8 = (idx & 15) * 8;
    f16x8 v = *reinterpret_cast<const f16x8*>(yh + (size_t)idx * 8);
    float4 o0, o1;
    o0.x = (float)v[0] * sc_sh[col8 + 0] + sh_sh[col8 + 0];
    o0.y = (float)v[1] * sc_sh[col8 + 1] + sh_sh[col8 + 1];
    o0.z = (float)v[2] * sc_sh[col8 + 2] + sh_sh[col8 + 2];
    o0.w = (float)v[3] * sc_sh[col8 + 3] + sh_sh[col8 + 3];
    o1.x = (float)v[4] * sc_sh[col8 + 4] + sh_sh[col8 + 4];
    o1.y = (float)v[5] * sc_sh[col8 + 5] + sh_sh[col8 + 5];
    o1.z = (float)v[6] * sc_sh[col8 + 6] + sh_sh[col8 + 6];
    o1.w = (float)v[7] * sc_sh[col8 + 7] + sh_sh[col8 + 7];
    *reinterpret_cast<float4*>(out + (size_t)idx * 8)     = o0;
    *reinterpret_cast<float4*>(out + (size_t)idx * 8 + 4) = o1;
}

extern "C" void kernel_launch(void* const* d_in, const int* in_sizes, int n_in,
                              void* d_out, int out_size, void* d_ws, size_t ws_size,
                              hipStream_t stream) {
    (void)n_in; (void)out_size; (void)ws_size;
    const float* x     = (const float*)d_in[0];
    const int*   src   = (const int*)d_in[1];
    const int*   dst   = (const int*)d_in[2];
    const float* we    = (const float*)d_in[3];
    const float* W     = (const float*)d_in[4];
    const float* gamma = (const float*)d_in[5];
    const float* beta  = (const float*)d_in[6];
    int N = in_sizes[0] / F;      // 50000 (src ids fit 25 bits)
    int E = in_sizes[1];          // 800000

    int NF  = (N + 127) / 128;    // buckets of 128 nodes (391)
    int Epb = (((E + NPB - 1) / NPB) + 3) & ~3;   // multiple of 4 for int4 path

    char* ws = (char*)d_ws;
    size_t off = 0;
    auto alloc = [&](size_t bytes) {
        void* p = ws + off;
        off += (bytes + 255) & ~(size_t)255;
        return p;
    };
    _Float16* xh     = (_Float16*)alloc((size_t)N * F * sizeof(_Float16));
    _Float16* aggh   = (_Float16*)alloc((size_t)N * F * sizeof(_Float16));
    _Float16* yh     = (_Float16*)alloc((size_t)N * F * sizeof(_Float16));
    _Float16* wh     = (_Float16*)alloc((size_t)F * 2 * F * sizeof(_Float16));
    float* stats     = (float*)alloc(2 * F * sizeof(float));   // colsum | colsumsq
    int*   histA     = (int*)alloc((size_t)512 * NPB * sizeof(int));
    int*   cursorRel = (int*)alloc((size_t)512 * NPB * sizeof(int));
    int*   tot       = (int*)alloc((size_t)512 * sizeof(int));
    int*   bktptr    = (int*)alloc((size_t)(512 + 1) * sizeof(int));
    int2*  payload   = (int2*)alloc((size_t)E * sizeof(int2));
    float* colsum    = stats;
    float* colsumsq  = stats + F;

    float* y = (float*)d_out;

    // phase 0: cvt_x | cvt_w | pa1 histogram (independent; one launch)
    int n4x = N * F / 4, n4w = 2 * F * F / 4;
    int nbx = (n4x + 255) / 256, nbw = (n4w + 255) / 256;
    hipLaunchKernelGGL(k_phase0, dim3(NPB + nbx + nbw), dim3(256), 0, stream,
                       x, xh, n4x, W, wh, n4w, dst, histA, E, Epb, NF, nbx);

    // parallel cursor build
    hipLaunchKernelGGL(k_pa2a, dim3(NF), dim3(256), 0, stream,
                       histA, cursorRel, tot);
    hipLaunchKernelGGL(k_pa2b, dim3(1), dim3(256), 0, stream,
                       tot, bktptr, stats, NF);
    hipLaunchKernelGGL(k_pa3, dim3(NPB), dim3(256), 0, stream,
                       dst, src, we, cursorRel, bktptr, payload, E, Epb, NF);

    // fused per-bucket sort + paired-row register-pull aggregation
    hipLaunchKernelGGL(k_sortagg, dim3(NF), dim3(512), 0, stream,
                       xh, bktptr, payload, aggh, N);

    // MFMA GEMM (W in LDS, 8 waves) + fused stats, f16 y
    hipLaunchKernelGGL(k_gemm_mfma, dim3((N + 127) / 128), dim3(512), 0, stream,
                       xh, aggh, wh, yh, colsum, colsumsq, N);

    // BN finalize + normalize (f16 y -> f32 out)
    hipLaunchKernelGGL(k_norm, dim3((N * F / 8 + 255) / 256), dim3(256), 0, stream,
                       yh, y, colsum, colsumsq, gamma, beta, 1.0f / (float)N, N * F / 8);
}

// Round 17
// 91.911 us; speedup vs baseline: 1.9227x; 1.9227x over previous
//
#include <hip/hip_runtime.h>

#define F 128            // F_IN == F_OUT == 128
#define EPSV 1e-5f
#define NPB 256          // scatter blocks (phase A)
#define CAP 5120         // max edges per 128-node bucket (mean 2048)

typedef _Float16 f16x8 __attribute__((ext_vector_type(8)));
typedef _Float16 f16x4 __attribute__((ext_vector_type(4)));
typedef _Float16 f16x2 __attribute__((ext_vector_type(2)));
typedef float    f32x4 __attribute__((ext_vector_type(4)));

#define SRCMASK 0x1FFFFFF   // low 25 bits: src id; bits 25..31: dst&127

// ---------------- Phase 0 (fused): cvt_x | cvt_w | pa1 histogram ------------
__global__ __launch_bounds__(256) void k_phase0(
        const float* __restrict__ x, _Float16* __restrict__ xh, int n4x,
        const float* __restrict__ W, _Float16* __restrict__ wh, int n4w,
        const int* __restrict__ dst, int* __restrict__ histA,
        int E, int Epb, int NF, int nbx) {
    int t = threadIdx.x, b = blockIdx.x;
    if (b < NPB) {
        __shared__ int h[512];
        h[t] = 0; h[t + 256] = 0;
        __syncthreads();
        int beg = b * Epb;
        int end = min(beg + Epb, E);
        for (int i = beg + t; i < end; i += 256)
            atomicAdd(&h[dst[i] >> 7], 1);
        __syncthreads();
        for (int f = t; f < NF; f += 256)
            histA[f * NPB + b] = h[f];
    } else if (b < NPB + nbx) {
        int i = (b - NPB) * 256 + t;
        if (i >= n4x) return;
        float4 v = *reinterpret_cast<const float4*>(x + (size_t)i * 4);
        f16x4 o = { (_Float16)v.x, (_Float16)v.y, (_Float16)v.z, (_Float16)v.w };
        *reinterpret_cast<f16x4*>(xh + (size_t)i * 4) = o;
    } else {
        int i = (b - NPB - nbx) * 256 + t;
        if (i >= n4w) return;
        float4 v = *reinterpret_cast<const float4*>(W + (size_t)i * 4);
        f16x4 o = { (_Float16)v.x, (_Float16)v.y, (_Float16)v.z, (_Float16)v.w };
        *reinterpret_cast<f16x4*>(wh + (size_t)i * 4) = o;
    }
}

// ---------------- Phase A2a: per-bucket exclusive scan over the NPB blocks --
__global__ __launch_bounds__(256) void k_pa2a(
        const int* __restrict__ histA, int* __restrict__ cursorRel,
        int* __restrict__ tot) {
    __shared__ int wsum[4];
    int f = blockIdx.x, t = threadIdx.x;
    int lane = t & 63, wv = t >> 6;
    int v = histA[f * NPB + t];
    int sc = v;
    #pragma unroll
    for (int off = 1; off < 64; off <<= 1) {
        int o = __shfl_up(sc, off);
        if (lane >= off) sc += o;
    }
    if (lane == 63) wsum[wv] = sc;
    __syncthreads();
    int woff = 0;
    for (int i = 0; i < wv; ++i) woff += wsum[i];
    cursorRel[f * NPB + t] = woff + sc - v;
    if (t == 255) tot[f] = woff + sc;
}

// ---------------- Phase A2b: scan bucket totals -> bktptr; zero stats -------
__global__ __launch_bounds__(256) void k_pa2b(
        const int* __restrict__ tot, int* __restrict__ bktptr,
        float* __restrict__ stats, int NF) {
    int t = threadIdx.x;
    stats[t] = 0.f;
    if (t < 64) {
        int carry = 0;
        for (int base = 0; base < NF; base += 64) {
            int i = base + t;
            int v = (i < NF) ? tot[i] : 0;
            int sc = v;
            #pragma unroll
            for (int off = 1; off < 64; off <<= 1) {
                int o = __shfl_up(sc, off);
                if (t >= off) sc += o;
            }
            if (i < NF) bktptr[i] = carry + sc - v;
            carry += __shfl(sc, 63);
        }
        if (t == 0) bktptr[NF] = carry;   // == E
    }
}

// ---------------- Phase A3: scatter packed payload into bucket order --------
__global__ __launch_bounds__(256) void k_pa3(
        const int* __restrict__ dst, const int* __restrict__ src,
        const float* __restrict__ we, const int* __restrict__ cursorRel,
        const int* __restrict__ bktptr,
        int2* __restrict__ payload, int E, int Epb, int NF) {
    __shared__ int cur[512];
    int t = threadIdx.x, b = blockIdx.x;
    for (int f = t; f < NF; f += 256)
        cur[f] = bktptr[f] + cursorRel[f * NPB + b];
    __syncthreads();
    int beg = b * Epb;                       // Epb % 4 == 0 -> 16B-aligned
    int end = min(beg + Epb, E);
    for (int i0 = beg + t * 4; i0 < end; i0 += 1024) {
        int d[4], s[4]; float w[4];
        if (i0 + 3 < end) {
            int4   d4 = *reinterpret_cast<const int4*>(dst + i0);
            int4   s4 = *reinterpret_cast<const int4*>(src + i0);
            float4 w4 = *reinterpret_cast<const float4*>(we + i0);
            d[0] = d4.x; d[1] = d4.y; d[2] = d4.z; d[3] = d4.w;
            s[0] = s4.x; s[1] = s4.y; s[2] = s4.z; s[3] = s4.w;
            w[0] = w4.x; w[1] = w4.y; w[2] = w4.z; w[3] = w4.w;
        } else {
            #pragma unroll
            for (int u = 0; u < 4; ++u) {
                int i = min(i0 + u, E - 1);
                d[u] = dst[i]; s[u] = src[i]; w[u] = we[i];
            }
        }
        int slot[4];
        #pragma unroll
        for (int u = 0; u < 4; ++u)
            if (i0 + u < end) slot[u] = atomicAdd(&cur[d[u] >> 7], 1);
        #pragma unroll
        for (int u = 0; u < 4; ++u)
            if (i0 + u < end)
                payload[slot[u]] = make_int2(s[u] | ((d[u] & 127) << 25),
                                             __float_as_int(w[u]));
    }
}

// ---------------- Fused sort + aggregate: one block per 128-node bucket -----
// Phase 1: counting-sort bucket edges into LDS (node order).
// Phase 2: 8 waves x 16 nodes, branchless unroll-8 register pull (r14-proven).
__global__ __launch_bounds__(512) void k_sortagg(
        const _Float16* __restrict__ xh, const int* __restrict__ bktptr,
        const int2* __restrict__ payload, _Float16* __restrict__ aggh, int N) {
    __shared__ int2 pl[CAP];                  // 40 KB
    __shared__ int h[128], hs[129], cur[128];
    int t = threadIdx.x, f = blockIdx.x;
    int beg = bktptr[f], end = bktptr[f + 1];
    int cnt = min(end - beg, CAP);
    if (t < 128) h[t] = 0;
    __syncthreads();
    for (int i = t; i < cnt; i += 512)
        atomicAdd(&h[(payload[beg + i].x >> 25) & 127], 1);
    __syncthreads();
    if (t < 64) {   // wave 0: exclusive scan of h[0..128)
        int v0 = h[t], s0 = v0;
        #pragma unroll
        for (int off = 1; off < 64; off <<= 1) {
            int o = __shfl_up(s0, off);
            if (t >= off) s0 += o;
        }
        int tot0 = __shfl(s0, 63);
        hs[t] = s0 - v0;
        int v1 = h[64 + t], s1 = v1;
        #pragma unroll
        for (int off = 1; off < 64; off <<= 1) {
            int o = __shfl_up(s1, off);
            if (t >= off) s1 += o;
        }
        hs[64 + t] = tot0 + s1 - v1;
    }
    __syncthreads();
    if (t < 128) cur[t] = hs[t];
    if (t == 128) hs[128] = cnt;
    __syncthreads();
    for (int i = t; i < cnt; i += 512) {
        int2 p = payload[beg + i];
        int r = (p.x >> 25) & 127;
        int pos = atomicAdd(&cur[r], 1);
        pl[pos] = p;
    }
    __syncthreads();

    int wv = t >> 6, lane = t & 63;
    int row0 = f << 7;
    #pragma unroll 1
    for (int k = 0; k < 16; ++k) {
        int r = wv * 16 + k;
        int n = row0 + r;
        if (n >= N) break;
        int b0 = hs[r], b1 = hs[r + 1];
        float ax = 0.f, ay = 0.f;
        for (int i = b0; i < b1; i += 8) {
            int2 p[8];
            #pragma unroll
            for (int u = 0; u < 8; ++u)
                p[u] = pl[min(i + u, b1 - 1)];   // clamp to node's own last edge
            f16x2 v[8];
            #pragma unroll
            for (int u = 0; u < 8; ++u)
                v[u] = *reinterpret_cast<const f16x2*>(
                    xh + (size_t)(p[u].x & SRCMASK) * F + lane * 2);
            #pragma unroll
            for (int u = 0; u < 8; ++u) {
                float wu = (i + u < b1) ? __int_as_float(p[u].y) : 0.f;
                ax += wu * (float)v[u][0];
                ay += wu * (float)v[u][1];
            }
        }
        f16x2 o = { (_Float16)ax, (_Float16)ay };
        *reinterpret_cast<f16x2*>(aggh + (size_t)n * F + lane * 2) = o;
    }
}

// ---------------- MFMA GEMM: 512 thr / 8 waves, 16 rows per wave ------------
__global__ __launch_bounds__(512) void k_gemm_mfma(
        const _Float16* __restrict__ xh, const _Float16* __restrict__ aggh,
        const _Float16* __restrict__ wh, _Float16* __restrict__ yh,
        float* __restrict__ colsum, float* __restrict__ colsumsq, int N) {
    __shared__ _Float16 lds_w[32768];                 // 64 KB, XOR-swizzled
    __shared__ float lds_s[8][128], lds_q[8][128];
    int t = threadIdx.x, w = t >> 6, l = t & 63;
    int lo16 = l & 15, hi4 = l >> 4;

    // stage W: 4096 chunks of 16B (8 f16); 32 chunks per 512B row.
    #pragma unroll
    for (int i = 0; i < 8; ++i) {
        int c = i * 512 + t;
        int o = c >> 5, kc = c & 31;
        f16x8 v = *reinterpret_cast<const f16x8*>(wh + (size_t)c * 8);
        int byte = (o * 512 + kc * 16) ^ ((o & 7) << 4);
        *reinterpret_cast<f16x8*>((char*)lds_w + byte) = v;
    }
    __syncthreads();

    int rows0 = blockIdx.x * 128 + w * 16;
    int ra0 = rows0 + lo16;
    if (ra0 >= N) ra0 = N - 1;                // clamp; discarded in epilogue

    f32x4 acc0[8] = {};
    #pragma unroll
    for (int kb = 0; kb < 8; ++kb) {
        const _Float16* base = (kb < 4) ? xh : aggh;
        int koff = (kb & 3) * 32 + hi4 * 8;
        f16x8 a0 = *reinterpret_cast<const f16x8*>(base + (size_t)ra0 * F + koff);
        #pragma unroll
        for (int ct = 0; ct < 8; ++ct) {
            int o = ct * 16 + lo16;
            int byte = (o * 512 + kb * 64 + hi4 * 16) ^ ((o & 7) << 4);
            f16x8 b = *reinterpret_cast<const f16x8*>((char*)lds_w + byte);
            acc0[ct] = __builtin_amdgcn_mfma_f32_16x16x32_f16(a0, b, acc0[ct], 0, 0, 0);
        }
    }

    #pragma unroll
    for (int ct = 0; ct < 8; ++ct) {
        float sv = 0.f, qv = 0.f;
        int col = ct * 16 + lo16;
        #pragma unroll
        for (int r = 0; r < 4; ++r) {
            int row0 = rows0 + hi4 * 4 + r;
            float v0 = acc0[ct][r];
            if (row0 < N) {
                yh[(size_t)row0 * F + col] = (_Float16)v0;
                sv += v0; qv += v0 * v0;
            }
        }
        sv += __shfl_xor(sv, 16); sv += __shfl_xor(sv, 32);
        qv += __shfl_xor(qv, 16); qv += __shfl_xor(qv, 32);
        if (l < 16) {
            lds_s[w][col] = sv;
            lds_q[w][col] = qv;
        }
    }
    __syncthreads();
    if (t < 128) {
        float S = 0.f, Q = 0.f;
        #pragma unroll
        for (int wv = 0; wv < 8; ++wv) {
            S += lds_s[wv][t];
            Q += lds_q[wv][t];
        }
        atomicAdd(&colsum[t], S);
        atomicAdd(&colsumsq[t], Q);
    }
}

// ---------------- BatchNorm: finalize + normalize (f16 y -> f32 out) --------
__global__ __launch_bounds__(256) void k_norm(
        const _Float16* __restrict__ yh, float* __restrict__ out,
        const float* __restrict__ colsum, const float* __restrict__ colsumsq,
        const float* __restrict__ gamma, const float* __restrict__ beta,
        float ninv, int total8) {
    __shared__ float sc_sh[F], sh_sh[F];
    int t = threadIdx.x;
    if (t < F) {
        float mean = colsum[t] * ninv;
        float var = colsumsq[t] * ninv - mean * mean;
        float rstd = rsqrtf(var + EPSV);
        float sc = gamma[t] * rstd;
        sc_sh[t] = sc;
        sh_sh[t] = beta[t] - mean * sc;
    }
    __syncthreads();
    int idx = blockIdx.x * 256 + t;
    if (idx >= total8) return;
    int col8 = (idx & 15) * 8;
    f16x8 v = *reinterpret_cast<const f16x8*>(yh + (size_t)idx * 8);
    float4 o0, o1;
    o0.x = (float)v[0] * sc_sh[col8 + 0] + sh_sh[col8 + 0];
    o0.y = (float)v[1] * sc_sh[col8 + 1] + sh_sh[col8 + 1];
    o0.z = (float)v[2] * sc_sh[col8 + 2] + sh_sh[col8 + 2];
    o0.w = (float)v[3] * sc_sh[col8 + 3] + sh_sh[col8 + 3];
    o1.x = (float)v[4] * sc_sh[col8 + 4] + sh_sh[col8 + 4];
    o1.y = (float)v[5] * sc_sh[col8 + 5] + sh_sh[col8 + 5];
    o1.z = (float)v[6] * sc_sh[col8 + 6] + sh_sh[col8 + 6];
    o1.w = (float)v[7] * sc_sh[col8 + 7] + sh_sh[col8 + 7];
    *reinterpret_cast<float4*>(out + (size_t)idx * 8)     = o0;
    *reinterpret_cast<float4*>(out + (size_t)idx * 8 + 4) = o1;
}

extern "C" void kernel_launch(void* const* d_in, const int* in_sizes, int n_in,
                              void* d_out, int out_size, void* d_ws, size_t ws_size,
                              hipStream_t stream) {
    (void)n_in; (void)out_size; (void)ws_size;
    const float* x     = (const float*)d_in[0];
    const int*   src   = (const int*)d_in[1];
    const int*   dst   = (const int*)d_in[2];
    const float* we    = (const float*)d_in[3];
    const float* W     = (const float*)d_in[4];
    const float* gamma = (const float*)d_in[5];
    const float* beta  = (const float*)d_in[6];
    int N = in_sizes[0] / F;      // 50000 (src ids fit 25 bits)
    int E = in_sizes[1];          // 800000

    int NF  = (N + 127) / 128;    // buckets of 128 nodes (391)
    int Epb = (((E + NPB - 1) / NPB) + 3) & ~3;   // multiple of 4 for int4 path

    char* ws = (char*)d_ws;
    size_t off = 0;
    auto alloc = [&](size_t bytes) {
        void* p = ws + off;
        off += (bytes + 255) & ~(size_t)255;
        return p;
    };
    _Float16* xh     = (_Float16*)alloc((size_t)N * F * sizeof(_Float16));
    _Float16* aggh   = (_Float16*)alloc((size_t)N * F * sizeof(_Float16));
    _Float16* yh     = (_Float16*)alloc((size_t)N * F * sizeof(_Float16));
    _Float16* wh     = (_Float16*)alloc((size_t)F * 2 * F * sizeof(_Float16));
    float* stats     = (float*)alloc(2 * F * sizeof(float));   // colsum | colsumsq
    int*   histA     = (int*)alloc((size_t)512 * NPB * sizeof(int));
    int*   cursorRel = (int*)alloc((size_t)512 * NPB * sizeof(int));
    int*   tot       = (int*)alloc((size_t)512 * sizeof(int));
    int*   bktptr    = (int*)alloc((size_t)(512 + 1) * sizeof(int));
    int2*  payload   = (int2*)alloc((size_t)E * sizeof(int2));
    float* colsum    = stats;
    float* colsumsq  = stats + F;

    float* y = (float*)d_out;

    // phase 0: cvt_x | cvt_w | pa1 histogram (independent; one launch)
    int n4x = N * F / 4, n4w = 2 * F * F / 4;
    int nbx = (n4x + 255) / 256, nbw = (n4w + 255) / 256;
    hipLaunchKernelGGL(k_phase0, dim3(NPB + nbx + nbw), dim3(256), 0, stream,
                       x, xh, n4x, W, wh, n4w, dst, histA, E, Epb, NF, nbx);

    // parallel cursor build
    hipLaunchKernelGGL(k_pa2a, dim3(NF), dim3(256), 0, stream,
                       histA, cursorRel, tot);
    hipLaunchKernelGGL(k_pa2b, dim3(1), dim3(256), 0, stream,
                       tot, bktptr, stats, NF);
    hipLaunchKernelGGL(k_pa3, dim3(NPB), dim3(256), 0, stream,
                       dst, src, we, cursorRel, bktptr, payload, E, Epb, NF);

    // fused per-bucket sort + register-pull aggregation
    hipLaunchKernelGGL(k_sortagg, dim3(NF), dim3(512), 0, stream,
                       xh, bktptr, payload, aggh, N);

    // MFMA GEMM (W in LDS, 8 waves) + fused stats, f16 y
    hipLaunchKernelGGL(k_gemm_mfma, dim3((N + 127) / 128), dim3(512), 0, stream,
                       xh, aggh, wh, yh, colsum, colsumsq, N);

    // BN finalize + normalize (f16 y -> f32 out)
    hipLaunchKernelGGL(k_norm, dim3((N * F / 8 + 255) / 256), dim3(256), 0, stream,
                       yh, y, colsum, colsumsq, gamma, beta, 1.0f / (float)N, N * F / 8);
}